// Round 1
// baseline (2302.924 us; speedup 1.0000x reference)
//
#include <hip/hip_runtime.h>
#include <stdint.h>

// Problem constants (match reference)
#define NP 32    // num networks (P)
#define NH 128   // hidden (H)
#define NB 32    // batch (B)
#define NT 256   // time (T)
#define FH 512   // 4*H

typedef __attribute__((ext_vector_type(4))) float float4_t;
typedef __attribute__((ext_vector_type(8))) __bf16 bf16x8;

static __device__ __forceinline__ float4_t mfma_bf16(bf16x8 a, bf16x8 b, float4_t c) {
  return __builtin_amdgcn_mfma_f32_16x16x32_bf16(a, b, c, 0, 0, 0);
}

#define LOG2E 1.4426950408889634f

// Raw workgroup barrier: drains LDS ops only (cross-wave h visibility), does
// NOT drain vmcnt — pending global loads/stores stay in flight across it.
#define BAR() __asm__ volatile("s_waitcnt lgkmcnt(0)\n\ts_barrier" ::: "memory")

// R9: two ANTI-PHASED streams per CU (16 waves, 128 blocks of 1024).
// Step model (R2..R8): step ~ MFMA_pipe(795) + trans/VALU issue + exposure
// (~700); the adds are STRUCTURAL (all waves phase-locked). Fix: waves 0-7
// run stream A, waves 8-15 stream B, roles swapped each half-iteration:
//   slot1: A=MFMA(t)      | B=act+write(t-1)   BAR
//   slot2: A=act+write(t) | B=MFMA(t)          BAR
// Every slot keeps the matrix pipe fed (2 MFMA-role waves/SIMD) while the
// other role's trans chain + LDS roundtrip hide under it. Shared barriers
// GUARANTEE anti-phase. Weights shared (same net per block) so per-wave
// VGPR stays ~108 <= 128 (16-wave tier; second block can't co-reside ->
// exactly 1 block/CU on 128 CUs).
// Kept from R3..R8: x-MFMAs before h-MFMAs (fills ds_read latency),
// c pre-scaled by -2log2e, pointer-incremented scalar-guarded x prefetch,
// cndmask batch-select (no DS/cross-lane ops), head after h-frag read.
__global__ __launch_bounds__(1024, 1) void clstm_fused(
    const float* __restrict__ X, const float* __restrict__ Wih,
    const float* __restrict__ Whh, const float* __restrict__ bih,
    const float* __restrict__ bhh, const float* __restrict__ Wout,
    const float* __restrict__ bout, float* __restrict__ out)
{
  const int net = blockIdx.x >> 2, pair = blockIdx.x & 3;
  const int tid = threadIdx.x;
  const int w = tid >> 6, lane = tid & 63;
  const int str = w >> 3;        // stream id: waves 0-7 -> A, 8-15 -> B
  const int wl = w & 7;          // within-stream wave id (column group)
  const int quad = lane >> 4, l16 = lane & 15;
  const int bq = pair * 2 + str; // batch-group of this wave's stream

  // h A-fragments per stream, double buffered, 4 DISTINCT rows:
  // [stream][buf][kc][kquad][m<4][j]
  __shared__ __bf16 hfrag[2][2][4][4][4][8];   // 4 KB total

  { // zero ALL buffers (h0 = 0): 4KB = 1024 ints, 1 per thread
    ((int*)hfrag)[tid] = 0;
  }
  __syncthreads();  // once, outside the loop

  // ---- load weights into register B-fragments (one-time, shared net) ----
  // B-frag layout for 16x16x32: lane holds B[k = quad*8 + j][n = l16].
  bf16x8 bfrag[4][5];
  float4_t bias4[4];
#pragma unroll
  for (int g = 0; g < 4; ++g) {
    const float scale = (g == 2) ? (-2.0f*LOG2E) : (-LOG2E);
    const int col = g*NH + wl*16 + l16;
#pragma unroll
    for (int kc = 0; kc < 5; ++kc) {
      const float* src = (kc == 0) ? (Wih + ((size_t)net*FH + col)*NP + quad*8)
                                   : (Whh + ((size_t)net*FH + col)*NH + (kc-1)*32 + quad*8);
      bf16x8 bf;
#pragma unroll
      for (int j = 0; j < 8; ++j) bf[j] = (__bf16)(src[j] * scale);
      bfrag[g][kc] = bf;
    }
    const float b = (bih[net*FH + col] + bhh[net*FH + col]) * scale;
    bias4[g] = (float4_t){b, b, b, b};
  }

  // head B-frags: B[k][n] = wout[k] broadcast over all 16 cols n.
  bf16x8 wof[4];
#pragma unroll
  for (int kc = 0; kc < 4; ++kc) {
    const float* wp = Wout + net*NH + kc*32 + quad*8;
#pragma unroll
    for (int j = 0; j < 8; ++j) wof[kc][j] = (__bf16)wp[j];
  }
  const float bo = bout[net];

  // c state, PRE-SCALED by -2log2e (saves a mul on the h critical chain)
  float cs = 0.f;
  const float S2 = -2.0f*LOG2E;

  // x A-frag source: row l16 -> batch bq*4 + (l16&3) (4x dup)
  const float* xrow = X + (size_t)(bq*4 + (l16 & 3))*(NT*NP) + quad*8;

  // h write coords for unit u = wl*16 + l16; row = quad (this lane's batch)
  const int kcp = wl >> 1, q2 = ((wl & 1) << 1) | (l16 >> 3), jj = l16 & 7;

  // head store base: out[(bq*4 + r)*NT*NP + t*NP + net]
  float* outp = out + ((size_t)bq*4)*(NT*NP) + net;

  // preload + convert x for t=0; xp then walks t=1..NT-1
  bf16x8 ax;
  {
    float xv0[8];
    *(float4_t*)&xv0[0] = *(const float4_t*)xrow;
    *(float4_t*)&xv0[4] = *(const float4_t*)(xrow + 4);
#pragma unroll
    for (int j = 0; j < 8; ++j) ax[j] = (__bf16)xv0[j];
  }
  const float* xp = xrow + NP;
  float xv[8] = {0.f,0.f,0.f,0.f,0.f,0.f,0.f,0.f};

  float4_t acc[4];   // gate pre-activations; live across the slot barrier

  // ---- MFMA phase for step t: read h(t-1) frags, x+h MFMAs, fused head ----
  auto mfma_phase = [&](int t) {
    const int rd = t & 1;

    // 1. h A-frags (row = l16&3; 4-lane same-address broadcast)
    bf16x8 ah[4];
#pragma unroll
    for (int kc = 0; kc < 4; ++kc)
      ah[kc] = *(const bf16x8*)&hfrag[str][rd][kc][quad][l16 & 3][0];

    // 2. x-MFMAs first: no LDS dependence, fills ds_read latency
    float4_t accx[4];
#pragma unroll
    for (int g = 0; g < 4; ++g)
      accx[g] = mfma_bf16(ax, bfrag[g][0], bias4[g]);

    // 3. x prefetch for t+1 (scalar-guarded, pointer-incremented)
    if (t + 1 < NT) {
      *(float4_t*)&xv[0] = *(const float4_t*)xp;
      *(float4_t*)&xv[4] = *(const float4_t*)(xp + 4);
    }

    // 4. h-MFMAs: 4 gates, two parallel chains each (depth 2)
#pragma unroll
    for (int g = 0; g < 4; ++g) {
      float4_t a0 = mfma_bf16(ah[0], bfrag[g][1], accx[g]);
      float4_t a1 = mfma_bf16(ah[2], bfrag[g][3], (float4_t){0.f,0.f,0.f,0.f});
      a0 = mfma_bf16(ah[1], bfrag[g][2], a0);
      a1 = mfma_bf16(ah[3], bfrag[g][4], a1);
      acc[g] = a0 + a1;
    }

    // 5. fused head (wave wl==0 of this stream; ah = h_{t-1} -> out[t-1])
    if (wl == 0 && t > 0) {
      float4_t p0 = {bo, bo, bo, bo};
      float4_t p1 = {0.f, 0.f, 0.f, 0.f};
      p0 = mfma_bf16(ah[0], wof[0], p0);
      p1 = mfma_bf16(ah[2], wof[2], p1);
      p0 = mfma_bf16(ah[1], wof[1], p0);
      p1 = mfma_bf16(ah[3], wof[3], p1);
      float4_t po = p0 + p1;
      if (lane == 0) {   // quad 0: C rows 0..3 = batches 0..3
#pragma unroll
        for (int r = 0; r < 4; ++r)
          outp[(size_t)r*(NT*NP) + (t - 1)*NP] = po[r];
      }
    }

    // 6. convert next x; advance pointer
#pragma unroll
    for (int j = 0; j < 8; ++j) ax[j] = (__bf16)xv[j];
    xp += NP;
  };

  // ---- ACT phase for step t: select batch, activations, write h(t) ----
  auto act_phase = [&](int t) {
    const int wr = (t + 1) & 1;

    // select this lane's batch (= quad) via cndmask, NOT shuffles
    float gv[4];
#pragma unroll
    for (int g = 0; g < 4; ++g) {
      float a01 = (quad & 1) ? acc[g][1] : acc[g][0];
      float a23 = (quad & 1) ? acc[g][3] : acc[g][2];
      gv[g] = (quad & 2) ? a23 : a01;
    }

    // activation + state update: ONE (batch,unit) pair per lane
    float h;
    {
      float ei = __builtin_amdgcn_exp2f(gv[0]);
      float ig = __builtin_amdgcn_rcpf(1.0f + ei);            // sigmoid(i)
      float ef = __builtin_amdgcn_exp2f(gv[1]);
      float fg = __builtin_amdgcn_rcpf(1.0f + ef);            // sigmoid(f)
      float eg = __builtin_amdgcn_exp2f(fminf(gv[2], 126.0f));
      float rg = __builtin_amdgcn_rcpf(1.0f + eg);
      float t0 = S2 * rg;
      float gg2 = t0 - t0 * eg;                               // tanh(g)*S2
      float eo = __builtin_amdgcn_exp2f(gv[3]);
      float og = __builtin_amdgcn_rcpf(1.0f + eo);            // sigmoid(o)
      cs = fg * cs + ig * gg2;                                // c * S2
      float ec = __builtin_amdgcn_exp2f(fminf(cs, 126.0f));
      float rc = __builtin_amdgcn_rcpf(1.0f + ec);
      float th = rc - ec * rc;                                // tanh(c)
      h = og * th;
    }

    // write h' (bf16): 1 ds_write_b16, row = quad
    hfrag[str][wr][kcp][q2][quad][jj] = (__bf16)h;
  };

  // ---- main loop: 2 slots/iter, both streams advance one step per iter ----
  // Stream A: MFMA(t) in slot1, ACT(t) in slot2.
  // Stream B: ACT(t-1) in slot1, MFMA(t) in slot2.
  // Barriers are OUTSIDE the role branches: all 16 waves hit every BAR.
  for (int it = 0; it <= NT; ++it) {
    if (str == 0) { if (it < NT) mfma_phase(it); }
    else          { if (it > 0)  act_phase(it - 1); }
    BAR();
    if (str == 0) { if (it < NT) act_phase(it); }
    else          { if (it < NT) mfma_phase(it); }
    BAR();
  }

  // ---- epilogue: head for t = NT-1, both streams (h in hfrag[str][NT&1]) --
  if (wl == 0) {
    bf16x8 ahf[4];
#pragma unroll
    for (int kc = 0; kc < 4; ++kc)
      ahf[kc] = *(const bf16x8*)&hfrag[str][NT & 1][kc][quad][l16 & 3][0];
    float4_t p0 = {bo, bo, bo, bo};
    float4_t p1 = {0.f, 0.f, 0.f, 0.f};
    p0 = mfma_bf16(ahf[0], wof[0], p0);
    p1 = mfma_bf16(ahf[2], wof[2], p1);
    p0 = mfma_bf16(ahf[1], wof[1], p0);
    p1 = mfma_bf16(ahf[3], wof[3], p1);
    float4_t po = p0 + p1;
    if (lane == 0) {
#pragma unroll
      for (int r = 0; r < 4; ++r)
        outp[(size_t)r*(NT*NP) + (NT - 1)*NP] = po[r];
    }
  }
}

extern "C" void kernel_launch(void* const* d_in, const int* in_sizes, int n_in,
                              void* d_out, int out_size, void* d_ws, size_t ws_size,
                              hipStream_t stream) {
  const float* X    = (const float*)d_in[0];
  const float* Wih  = (const float*)d_in[1];
  const float* Whh  = (const float*)d_in[2];
  const float* bih  = (const float*)d_in[3];
  const float* bhh  = (const float*)d_in[4];
  const float* Wout = (const float*)d_in[5];
  const float* bout = (const float*)d_in[6];
  float* out = (float*)d_out;
  (void)in_sizes; (void)n_in; (void)out_size; (void)d_ws; (void)ws_size;

  // 128 blocks = 32 nets x 4 stream-pairs; 1024 thr = 16 waves = 2 streams.
  clstm_fused<<<128, 1024, 0, stream>>>(X, Wih, Whh, bih, bhh, Wout, bout, out);
}

// Round 2
// 1600.437 us; speedup vs baseline: 1.4389x; 1.4389x over previous
//
#include <hip/hip_runtime.h>
#include <stdint.h>

// Problem constants (match reference)
#define NP 32    // num networks (P)
#define NH 128   // hidden (H)
#define NB 32    // batch (B)
#define NT 256   // time (T)
#define FH 512   // 4*H

typedef __attribute__((ext_vector_type(4))) float float4_t;
typedef __attribute__((ext_vector_type(8))) __bf16 bf16x8;

static __device__ __forceinline__ float4_t mfma_bf16(bf16x8 a, bf16x8 b, float4_t c) {
  return __builtin_amdgcn_mfma_f32_16x16x32_bf16(a, b, c, 0, 0, 0);
}

#define LOG2E 1.4426950408889634f

// Raw workgroup barrier: drains LDS ops only (cross-wave h visibility), does
// NOT drain vmcnt — pending global loads/stores stay in flight across it.
#define BAR() __asm__ volatile("s_waitcnt lgkmcnt(0)\n\ts_barrier" ::: "memory")

// R10: R9's anti-phase retry with the spill confounder removed.
// R9 post-mortem: __launch_bounds__(1024,1) let the allocator target 2
// blocks/CU -> 64-VGPR cap -> bfrag spilled to scratch (FETCH 42->598 MB,
// MfmaUtil 3%). Fix: __launch_bounds__(1024,4) => 4 waves/EU => exactly
// 1 block/CU => 128-VGPR cap. Also: lambdas -> macros (capture-by-ref
// arrays across a barrier risk scratch, rule-#20 family), and bias4[4]
// (16 regs of broadcast dups) -> scalar bsc[4] added in ACT (-12 VGPR).
//
// Anti-phase design (unchanged from R9): waves 0-7 stream A, 8-15 stream B,
// roles swapped each half-iteration:
//   slot1: A=MFMA(t)      | B=act+write(t-1)   BAR
//   slot2: A=act+write(t) | B=MFMA(t)          BAR
// Matrix pipe fed every slot (164 instr x 4.85 = 795 cyc) while the other
// stream's trans chain + LDS roundtrip hide under it. Shared barriers
// guarantee anti-phase. iter ~= 2x(795+sync) ~= 1740 cyc for 2 stream-steps
// -> ~186 us predicted vs R8's serial 2060 cyc/step (219 us).
// Kept from R3..R8: x-MFMAs before h-MFMAs, c pre-scaled by -2log2e,
// pointer-incremented scalar-guarded x prefetch, cndmask batch-select
// (no DS/cross-lane ops in loop), head after h-frag read.
__global__ __launch_bounds__(1024, 4) void clstm_fused(
    const float* __restrict__ X, const float* __restrict__ Wih,
    const float* __restrict__ Whh, const float* __restrict__ bih,
    const float* __restrict__ bhh, const float* __restrict__ Wout,
    const float* __restrict__ bout, float* __restrict__ out)
{
  const int net = blockIdx.x >> 2, pair = blockIdx.x & 3;
  const int tid = threadIdx.x;
  const int w = tid >> 6, lane = tid & 63;
  const int str = w >> 3;        // stream id: waves 0-7 -> A, 8-15 -> B
  const int wl = w & 7;          // within-stream wave id (column group)
  const int quad = lane >> 4, l16 = lane & 15;
  const int bq = pair * 2 + str; // batch-group of this wave's stream

  // h A-fragments per stream, double buffered, 4 DISTINCT rows:
  // [stream][buf][kc][kquad][m<4][j]
  __shared__ __bf16 hfrag[2][2][4][4][4][8];   // 4 KB total

  { // zero ALL buffers (h0 = 0): 4KB = 1024 ints, 1 per thread
    ((int*)hfrag)[tid] = 0;
  }
  __syncthreads();  // once, outside the loop

  // ---- load weights into register B-fragments (one-time, shared net) ----
  // B-frag layout for 16x16x32: lane holds B[k = quad*8 + j][n = l16].
  bf16x8 bfrag[4][5];
  float bsc[4];   // scalar bias per gate (added post-MFMA in ACT phase)
#pragma unroll
  for (int g = 0; g < 4; ++g) {
    const float scale = (g == 2) ? (-2.0f*LOG2E) : (-LOG2E);
    const int col = g*NH + wl*16 + l16;
#pragma unroll
    for (int kc = 0; kc < 5; ++kc) {
      const float* src = (kc == 0) ? (Wih + ((size_t)net*FH + col)*NP + quad*8)
                                   : (Whh + ((size_t)net*FH + col)*NH + (kc-1)*32 + quad*8);
      bf16x8 bf;
#pragma unroll
      for (int j = 0; j < 8; ++j) bf[j] = (__bf16)(src[j] * scale);
      bfrag[g][kc] = bf;
    }
    bsc[g] = (bih[net*FH + col] + bhh[net*FH + col]) * scale;
  }

  // head B-frags: B[k][n] = wout[k] broadcast over all 16 cols n.
  bf16x8 wof[4];
#pragma unroll
  for (int kc = 0; kc < 4; ++kc) {
    const float* wp = Wout + net*NH + kc*32 + quad*8;
#pragma unroll
    for (int j = 0; j < 8; ++j) wof[kc][j] = (__bf16)wp[j];
  }
  const float bo = bout[net];

  // c state, PRE-SCALED by -2log2e (saves a mul on the h critical chain)
  float cs = 0.f;
  const float S2 = -2.0f*LOG2E;

  // x A-frag source: row l16 -> batch bq*4 + (l16&3) (4x dup)
  const float* xrow = X + (size_t)(bq*4 + (l16 & 3))*(NT*NP) + quad*8;

  // h write coords for unit u = wl*16 + l16; row = quad (this lane's batch)
  const int kcp = wl >> 1, q2 = ((wl & 1) << 1) | (l16 >> 3), jj = l16 & 7;

  // head store base: out[(bq*4 + r)*NT*NP + t*NP + net]
  float* outp = out + ((size_t)bq*4)*(NT*NP) + net;

  // preload + convert x for t=0; xp then walks t=1..NT-1
  bf16x8 ax;
  {
    float xv0[8];
    *(float4_t*)&xv0[0] = *(const float4_t*)xrow;
    *(float4_t*)&xv0[4] = *(const float4_t*)(xrow + 4);
#pragma unroll
    for (int j = 0; j < 8; ++j) ax[j] = (__bf16)xv0[j];
  }
  const float* xp = xrow + NP;
  float xv[8] = {0.f,0.f,0.f,0.f,0.f,0.f,0.f,0.f};

  float4_t acc[4];   // gate pre-activations; live across the slot barrier

// ---- MFMA phase for step T_: read h(T_-1) frags, x+h MFMAs, fused head ----
#define MFMA_PHASE(T_)                                                        \
  do {                                                                        \
    const int rd_ = (T_) & 1;                                                 \
    bf16x8 ah_[4];                                                            \
    _Pragma("unroll")                                                         \
    for (int kc = 0; kc < 4; ++kc)                                            \
      ah_[kc] = *(const bf16x8*)&hfrag[str][rd_][kc][quad][l16 & 3][0];       \
    float4_t accx_[4];                                                        \
    _Pragma("unroll")                                                         \
    for (int g = 0; g < 4; ++g)                                               \
      accx_[g] = mfma_bf16(ax, bfrag[g][0], (float4_t){0.f,0.f,0.f,0.f});     \
    if ((T_) + 1 < NT) {                                                      \
      *(float4_t*)&xv[0] = *(const float4_t*)xp;                              \
      *(float4_t*)&xv[4] = *(const float4_t*)(xp + 4);                        \
    }                                                                         \
    _Pragma("unroll")                                                         \
    for (int g = 0; g < 4; ++g) {                                             \
      float4_t a0_ = mfma_bf16(ah_[0], bfrag[g][1], accx_[g]);                \
      float4_t a1_ = mfma_bf16(ah_[2], bfrag[g][3],                           \
                               (float4_t){0.f,0.f,0.f,0.f});                  \
      a0_ = mfma_bf16(ah_[1], bfrag[g][2], a0_);                              \
      a1_ = mfma_bf16(ah_[3], bfrag[g][4], a1_);                              \
      acc[g] = a0_ + a1_;                                                     \
    }                                                                         \
    if (wl == 0 && (T_) > 0) {                                                \
      float4_t p0_ = {bo, bo, bo, bo};                                        \
      float4_t p1_ = {0.f, 0.f, 0.f, 0.f};                                    \
      p0_ = mfma_bf16(ah_[0], wof[0], p0_);                                   \
      p1_ = mfma_bf16(ah_[2], wof[2], p1_);                                   \
      p0_ = mfma_bf16(ah_[1], wof[1], p0_);                                   \
      p1_ = mfma_bf16(ah_[3], wof[3], p1_);                                   \
      float4_t po_ = p0_ + p1_;                                               \
      if (lane == 0) {                                                        \
        _Pragma("unroll")                                                     \
        for (int r = 0; r < 4; ++r)                                           \
          outp[(size_t)r*(NT*NP) + ((T_) - 1)*NP] = po_[r];                   \
      }                                                                       \
    }                                                                         \
    _Pragma("unroll")                                                         \
    for (int j = 0; j < 8; ++j) ax[j] = (__bf16)xv[j];                        \
    xp += NP;                                                                 \
  } while (0)

// ---- ACT phase for step T_: select batch, bias, activations, write h ----
#define ACT_PHASE(T_)                                                         \
  do {                                                                        \
    const int wr_ = ((T_) + 1) & 1;                                           \
    float gv_[4];                                                             \
    _Pragma("unroll")                                                         \
    for (int g = 0; g < 4; ++g) {                                             \
      float a01_ = (quad & 1) ? acc[g][1] : acc[g][0];                        \
      float a23_ = (quad & 1) ? acc[g][3] : acc[g][2];                        \
      gv_[g] = ((quad & 2) ? a23_ : a01_) + bsc[g];                           \
    }                                                                         \
    float h_;                                                                 \
    {                                                                         \
      float ei_ = __builtin_amdgcn_exp2f(gv_[0]);                             \
      float ig_ = __builtin_amdgcn_rcpf(1.0f + ei_);                          \
      float ef_ = __builtin_amdgcn_exp2f(gv_[1]);                             \
      float fg_ = __builtin_amdgcn_rcpf(1.0f + ef_);                          \
      float eg_ = __builtin_amdgcn_exp2f(fminf(gv_[2], 126.0f));              \
      float rg_ = __builtin_amdgcn_rcpf(1.0f + eg_);                          \
      float t0_ = S2 * rg_;                                                   \
      float gg2_ = t0_ - t0_ * eg_;                                           \
      float eo_ = __builtin_amdgcn_exp2f(gv_[3]);                             \
      float og_ = __builtin_amdgcn_rcpf(1.0f + eo_);                          \
      cs = fg_ * cs + ig_ * gg2_;                                             \
      float ec_ = __builtin_amdgcn_exp2f(fminf(cs, 126.0f));                  \
      float rc_ = __builtin_amdgcn_rcpf(1.0f + ec_);                          \
      float th_ = rc_ - ec_ * rc_;                                            \
      h_ = og_ * th_;                                                         \
    }                                                                         \
    hfrag[str][wr_][kcp][q2][quad][jj] = (__bf16)h_;                          \
  } while (0)

  // ---- main loop: 2 slots/iter, both streams advance one step per iter ----
  // Stream A: MFMA(t) in slot1, ACT(t) in slot2.
  // Stream B: ACT(t-1) in slot1, MFMA(t) in slot2.
  // Barriers are OUTSIDE the role branches: all 16 waves hit every BAR.
  for (int it = 0; it <= NT; ++it) {
    if (str == 0) { if (it < NT) MFMA_PHASE(it); }
    else          { if (it > 0)  ACT_PHASE(it - 1); }
    BAR();
    if (str == 0) { if (it < NT) ACT_PHASE(it); }
    else          { if (it < NT) MFMA_PHASE(it); }
    BAR();
  }

  // ---- epilogue: head for t = NT-1, both streams (h in hfrag[str][NT&1]) --
  if (wl == 0) {
    bf16x8 ahf[4];
#pragma unroll
    for (int kc = 0; kc < 4; ++kc)
      ahf[kc] = *(const bf16x8*)&hfrag[str][NT & 1][kc][quad][l16 & 3][0];
    float4_t p0 = {bo, bo, bo, bo};
    float4_t p1 = {0.f, 0.f, 0.f, 0.f};
    p0 = mfma_bf16(ahf[0], wof[0], p0);
    p1 = mfma_bf16(ahf[2], wof[2], p1);
    p0 = mfma_bf16(ahf[1], wof[1], p0);
    p1 = mfma_bf16(ahf[3], wof[3], p1);
    float4_t po = p0 + p1;
    if (lane == 0) {
#pragma unroll
      for (int r = 0; r < 4; ++r)
        outp[(size_t)r*(NT*NP) + (NT - 1)*NP] = po[r];
    }
  }
}

extern "C" void kernel_launch(void* const* d_in, const int* in_sizes, int n_in,
                              void* d_out, int out_size, void* d_ws, size_t ws_size,
                              hipStream_t stream) {
  const float* X    = (const float*)d_in[0];
  const float* Wih  = (const float*)d_in[1];
  const float* Whh  = (const float*)d_in[2];
  const float* bih  = (const float*)d_in[3];
  const float* bhh  = (const float*)d_in[4];
  const float* Wout = (const float*)d_in[5];
  const float* bout = (const float*)d_in[6];
  float* out = (float*)d_out;
  (void)in_sizes; (void)n_in; (void)out_size; (void)d_ws; (void)ws_size;

  // 128 blocks = 32 nets x 4 stream-pairs; 1024 thr = 16 waves = 2 streams.
  clstm_fused<<<128, 1024, 0, stream>>>(X, Wih, Whh, bih, bhh, Wout, bout, out);
}

// Round 3
// 1051.814 us; speedup vs baseline: 2.1895x; 1.5216x over previous
//
#include <hip/hip_runtime.h>
#include <stdint.h>

// Problem constants (match reference)
#define NP 32    // num networks (P)
#define NH 128   // hidden (H)
#define NB 32    // batch (B)
#define NT 256   // time (T)
#define FH 512   // 4*H

typedef __attribute__((ext_vector_type(4))) float float4_t;
typedef __attribute__((ext_vector_type(8))) __bf16 bf16x8;

static __device__ __forceinline__ float4_t mfma_bf16(bf16x8 a, bf16x8 b, float4_t c) {
  return __builtin_amdgcn_mfma_f32_16x16x32_bf16(a, b, c, 0, 0, 0);
}

#define LOG2E 1.4426950408889634f

// Raw workgroup barrier: drains LDS ops only (cross-wave h visibility), does
// NOT drain vmcnt — pending global loads/stores stay in flight across it.
#define BAR() __asm__ volatile("s_waitcnt lgkmcnt(0)\n\ts_barrier" ::: "memory")

// R11: M=2 / 512 blocks -> 2 co-resident blocks per CU (statistical
// anti-phase). R9/R10 post-mortem: 1024-thr blocks force a 128-reg
// unified cap (16 waves resident => 4 waves/SIMD) below the ~145-reg
// working set -> unavoidable spills (VGPR=64, WRITE 35MB, MfmaUtil 4%).
// In-block anti-phase is infeasible; instead keep R8's EXACT 8-wave
// codegen (108 VGPR) and double the grid: 512 blocks = 32 nets x 16
// batch-groups x M=2 real batches (8x row-dup). 108 <= 128 => 4 waves/
// SIMD => 2 blocks/CU. When one block sits in its barrier/LDS exposure
// (~1150 cyc/step idle in R8: MfmaUtil 33 + nonMFMA-VALU ~11% => 56%
// idle), the co-resident block issues. Cost: MFMA pipe demand doubles
// (dup waste) => pair ~ max(1590 pipe, paths) ~ 1750-1950 cyc for TWO
// stream-steps vs R8's 2060 for one.
// Step-time model (validated R2-R8): step ~ MFMA_pipe(164 instr x 4.85)
// + trans/VALU issue + exposure(~1150). SESSION RULES: no DS-pipe ops in
// loop (R5); x via register prefetch only (R3); no deep dependent MFMA
// chains (R6).
// Dup trick (M=2): A rows hold batch l16&1 (8x dup) -> C reg r of quad q
// is batch r&1; lane adopts reg index = quad&1 (ONE cndmask, was 2).
// Micro (kept from R8): x-MFMAs before h-MFMAs (fills LDS latency);
// c-state pre-scaled by -2log2e; x prefetch pointer-incremented +
// scalar-guarded; head (wave 0, two 2-deep MFMA chains) after h-read.
__global__ __launch_bounds__(512, 4) void clstm_fused(
    const float* __restrict__ X, const float* __restrict__ Wih,
    const float* __restrict__ Whh, const float* __restrict__ bih,
    const float* __restrict__ bhh, const float* __restrict__ Wout,
    const float* __restrict__ bout, float* __restrict__ out)
{
  const int net = blockIdx.x >> 4, bq = blockIdx.x & 15;
  const int tid = threadIdx.x;
  const int w = tid >> 6, lane = tid & 63;
  const int quad = lane >> 4, l16 = lane & 15;

  // h A-fragments, double buffered: [buf][kc][kquad][m<4][j]
  // (m rows 2,3 unused at M=2; layout kept identical to R8)
  __shared__ __bf16 hfrag[2][4][4][4][8];   // 2 KB total

  { // zero BOTH buffers (h0 = 0): 2KB = 512 ints, 1 per thread
    ((int*)hfrag)[tid] = 0;
  }
  __syncthreads();  // once, outside the loop

  // ---- load weights into register B-fragments (one-time) ----
  // B-frag layout for 16x16x32: lane holds B[k = quad*8 + j][n = l16].
  bf16x8 bfrag[4][5];
  float4_t bias4[4];
#pragma unroll
  for (int g = 0; g < 4; ++g) {
    const float scale = (g == 2) ? (-2.0f*LOG2E) : (-LOG2E);
    const int col = g*NH + w*16 + l16;
#pragma unroll
    for (int kc = 0; kc < 5; ++kc) {
      const float* src = (kc == 0) ? (Wih + ((size_t)net*FH + col)*NP + quad*8)
                                   : (Whh + ((size_t)net*FH + col)*NH + (kc-1)*32 + quad*8);
      bf16x8 bf;
#pragma unroll
      for (int j = 0; j < 8; ++j) bf[j] = (__bf16)(src[j] * scale);
      bfrag[g][kc] = bf;
    }
    const float b = (bih[net*FH + col] + bhh[net*FH + col]) * scale;
    bias4[g] = (float4_t){b, b, b, b};
  }

  // head B-frags: B[k][n] = wout[k] broadcast over all 16 cols n.
  bf16x8 wof[4];
#pragma unroll
  for (int kc = 0; kc < 4; ++kc) {
    const float* wp = Wout + net*NH + kc*32 + quad*8;
#pragma unroll
    for (int j = 0; j < 8; ++j) wof[kc][j] = (__bf16)wp[j];
  }
  const float bo = bout[net];

  // c state, PRE-SCALED by -2log2e (saves a mul on the h critical chain)
  float cs = 0.f;
  const float S2 = -2.0f*LOG2E;

  // x A-frag source: row l16 -> batch bq*2 + (l16&1) (8x dup)
  const float* xrow = X + (size_t)(bq*2 + (l16 & 1))*(NT*NP) + quad*8;

  // h write coords for unit u = w*16 + l16; row = quad&1 (lane's batch)
  const int kcp = w >> 1, q2 = ((w & 1) << 1) | (l16 >> 3), jj = l16 & 7;
  const int mrow = quad & 1;

  // head store base: out[(bq*2 + r)*NT*NP + t*NP + net], stored by
  // wave 0, lane 0 (C regs 0,1 = batches 0,1).
  float* outp = out + ((size_t)bq*2)*(NT*NP) + net;

  // preload + convert x for t=0; xp then walks t=1..NT-1
  bf16x8 ax;
  {
    float xv0[8];
    *(float4_t*)&xv0[0] = *(const float4_t*)xrow;
    *(float4_t*)&xv0[4] = *(const float4_t*)(xrow + 4);
#pragma unroll
    for (int j = 0; j < 8; ++j) ax[j] = (__bf16)xv0[j];
  }
  const float* xp = xrow + NP;
  float xv[8] = {0.f,0.f,0.f,0.f,0.f,0.f,0.f,0.f};

  for (int t = 0; t < NT; ++t) {
    const int rd = t & 1, wr = rd ^ 1;

    // ---- 1. h A-frags (row = l16&1; 8-lane same-address broadcast) ----
    bf16x8 ah[4];
#pragma unroll
    for (int kc = 0; kc < 4; ++kc)
      ah[kc] = *(const bf16x8*)&hfrag[rd][kc][quad][l16 & 1][0];

    // ---- 2. x-MFMAs first: no LDS dependence, fills ds_read latency ----
    float4_t accx[4];
#pragma unroll
    for (int g = 0; g < 4; ++g)
      accx[g] = mfma_bf16(ax, bfrag[g][0], bias4[g]);

    // ---- 3. x prefetch for t+1 (scalar-guarded, pointer-incremented) ----
    if (t + 1 < NT) {
      *(float4_t*)&xv[0] = *(const float4_t*)xp;
      *(float4_t*)&xv[4] = *(const float4_t*)(xp + 4);
    }

    // ---- 4. h-MFMAs: 4 gates, two parallel chains each (depth 2) ----
    float4_t acc[4];
#pragma unroll
    for (int g = 0; g < 4; ++g) {
      float4_t a0 = mfma_bf16(ah[0], bfrag[g][1], accx[g]);
      float4_t a1 = mfma_bf16(ah[2], bfrag[g][3], (float4_t){0.f,0.f,0.f,0.f});
      a0 = mfma_bf16(ah[1], bfrag[g][2], a0);
      a1 = mfma_bf16(ah[3], bfrag[g][4], a1);
      acc[g] = a0 + a1;
    }

    // ---- 5. select this lane's batch (= quad&1): ONE cndmask per gate ----
    float gv[4];
#pragma unroll
    for (int g = 0; g < 4; ++g)
      gv[g] = (quad & 1) ? acc[g][1] : acc[g][0];

    // ---- 6. activation + state update: ONE (batch,unit) pair per lane ----
    // (quads 2,3 duplicate quads 0,1 — harmless, keeps all lanes uniform)
    float h;
    {
      float ei = __builtin_amdgcn_exp2f(gv[0]);
      float ig = __builtin_amdgcn_rcpf(1.0f + ei);            // sigmoid(i)
      float ef = __builtin_amdgcn_exp2f(gv[1]);
      float fg = __builtin_amdgcn_rcpf(1.0f + ef);            // sigmoid(f)
      float eg = __builtin_amdgcn_exp2f(fminf(gv[2], 126.0f));
      float rg = __builtin_amdgcn_rcpf(1.0f + eg);
      float t0 = S2 * rg;
      float gg2 = t0 - t0 * eg;                               // tanh(g)*S2
      float eo = __builtin_amdgcn_exp2f(gv[3]);
      float og = __builtin_amdgcn_rcpf(1.0f + eo);            // sigmoid(o)
      cs = fg * cs + ig * gg2;                                // c * S2
      float ec = __builtin_amdgcn_exp2f(fminf(cs, 126.0f));
      float rc = __builtin_amdgcn_rcpf(1.0f + ec);
      float th = rc - ec * rc;                                // tanh(c)
      h = og * th;
    }

    // ---- 7. write h' (bf16): 1 ds_write_b16, rows 0,1 only (quads 0,1) --
    if (quad < 2)
      hfrag[wr][kcp][q2][mrow][jj] = (__bf16)h;

    // ---- 8. fused head (wave 0; ah = h_{t-1} -> out[t-1]) ----
    if (w == 0 && t > 0) {
      float4_t p0 = {bo, bo, bo, bo};
      float4_t p1 = {0.f, 0.f, 0.f, 0.f};
      p0 = mfma_bf16(ah[0], wof[0], p0);
      p1 = mfma_bf16(ah[2], wof[2], p1);
      p0 = mfma_bf16(ah[1], wof[1], p0);
      p1 = mfma_bf16(ah[3], wof[3], p1);
      float4_t po = p0 + p1;
      if (lane == 0) {   // C regs 0,1 = batches 0,1
#pragma unroll
        for (int r = 0; r < 2; ++r)
          outp[(size_t)r*(NT*NP) + (t - 1)*NP] = po[r];
      }
    }

    // ---- 9. convert next x; advance pointer ----
#pragma unroll
    for (int j = 0; j < 8; ++j) ax[j] = (__bf16)xv[j];
    xp += NP;

    BAR();  // lgkmcnt-only barrier
  }

  // ---- epilogue: head for t = NT-1 (h_{NT-1} is in hfrag[NT&1]) ----
  if (w == 0) {
    bf16x8 ahf[4];
#pragma unroll
    for (int kc = 0; kc < 4; ++kc)
      ahf[kc] = *(const bf16x8*)&hfrag[NT & 1][kc][quad][l16 & 1][0];
    float4_t p0 = {bo, bo, bo, bo};
    float4_t p1 = {0.f, 0.f, 0.f, 0.f};
    p0 = mfma_bf16(ahf[0], wof[0], p0);
    p1 = mfma_bf16(ahf[2], wof[2], p1);
    p0 = mfma_bf16(ahf[1], wof[1], p0);
    p1 = mfma_bf16(ahf[3], wof[3], p1);
    float4_t po = p0 + p1;
    if (lane == 0) {
#pragma unroll
      for (int r = 0; r < 2; ++r)
        outp[(size_t)r*(NT*NP) + (NT - 1)*NP] = po[r];
    }
  }
}

extern "C" void kernel_launch(void* const* d_in, const int* in_sizes, int n_in,
                              void* d_out, int out_size, void* d_ws, size_t ws_size,
                              hipStream_t stream) {
  const float* X    = (const float*)d_in[0];
  const float* Wih  = (const float*)d_in[1];
  const float* Whh  = (const float*)d_in[2];
  const float* bih  = (const float*)d_in[3];
  const float* bhh  = (const float*)d_in[4];
  const float* Wout = (const float*)d_in[5];
  const float* bout = (const float*)d_in[6];
  float* out = (float*)d_out;
  (void)in_sizes; (void)n_in; (void)out_size; (void)d_ws; (void)ws_size;

  // 512 blocks = 32 nets x 16 batch-groups (M=2); 2 blocks co-resident/CU.
  clstm_fused<<<512, 512, 0, stream>>>(X, Wih, Whh, bih, bhh, Wout, bout, out);
}

// Round 4
// 383.140 us; speedup vs baseline: 6.0107x; 2.7452x over previous
//
#include <hip/hip_runtime.h>
#include <stdint.h>

// Problem constants (match reference)
#define NP 32    // num networks (P)
#define NH 128   // hidden (H)
#define NB 32    // batch (B)
#define NT 256   // time (T)
#define FH 512   // 4*H

typedef __attribute__((ext_vector_type(4))) float float4_t;
typedef __attribute__((ext_vector_type(8))) __bf16 bf16x8;

static __device__ __forceinline__ float4_t mfma_bf16(bf16x8 a, bf16x8 b, float4_t c) {
  return __builtin_amdgcn_mfma_f32_16x16x32_bf16(a, b, c, 0, 0, 0);
}

#define LOG2E 1.4426950408889634f

// Raw workgroup barrier: drains LDS ops only (cross-wave h visibility), does
// NOT drain vmcnt — pending global loads/stores stay in flight across it.
#define BAR() __asm__ volatile("s_waitcnt lgkmcnt(0)\n\ts_barrier" ::: "memory")

// R12: R11 grid (M=2, 512 blocks -> 2 blocks/CU statistical anti-phase)
// with R8's TRUSTED launch bounds.
// LAUNCH-BOUNDS SESSION RULE (R9/R10/R11 evidence): any second arg != 1
// drives this toolchain to an 8-waves/EU target => 64-VGPR cap => bfrag
// spills (FETCH 350+ MB, MfmaUtil <15%). (512,1) is the ONLY verified
// config giving 108 VGPR. Occupancy is NOT requested from the compiler:
// 108 VGPR x 4 waves = 432 <= 512/SIMD, so the HW scheduler co-schedules
// 2 blocks/CU on its own (R11 measured 45% occupancy).
// Theory: R8 step = 2060 cyc = MFMA_pipe(795) + VALU(~230) + exposure
// (~1030, barrier drain/LDS roundtrip/dep chains). A co-resident block
// fills the exposure: per step-pair busy = 2x(795+230) ~ 2050 cyc ~ one
// R8 critical path => ~2x throughput if interleave is clean.
// Cost of M=2: 8x A-row dup => chip-wide MFMA count doubles (pipe still
// under budget). SESSION RULES: no DS-pipe ops in loop (R5); x via
// register prefetch only (R3); no deep dependent MFMA chains (R6).
// Dup trick (M=2): A rows hold batch l16&1 -> C reg r = batch r&1; lane
// adopts reg index = quad&1 (ONE cndmask). Micro (kept from R8): x-MFMAs
// before h-MFMAs; c pre-scaled by -2log2e; pointer-incremented scalar-
// guarded x prefetch; head (wave 0) after h-frag read.
__global__ __launch_bounds__(512, 1) void clstm_fused(
    const float* __restrict__ X, const float* __restrict__ Wih,
    const float* __restrict__ Whh, const float* __restrict__ bih,
    const float* __restrict__ bhh, const float* __restrict__ Wout,
    const float* __restrict__ bout, float* __restrict__ out)
{
  const int net = blockIdx.x >> 4, bq = blockIdx.x & 15;
  const int tid = threadIdx.x;
  const int w = tid >> 6, lane = tid & 63;
  const int quad = lane >> 4, l16 = lane & 15;

  // h A-fragments, double buffered: [buf][kc][kquad][m<4][j]
  // (m rows 2,3 unused at M=2; layout kept identical to R8)
  __shared__ __bf16 hfrag[2][4][4][4][8];   // 2 KB total

  { // zero BOTH buffers (h0 = 0): 2KB = 512 ints, 1 per thread
    ((int*)hfrag)[tid] = 0;
  }
  __syncthreads();  // once, outside the loop

  // ---- load weights into register B-fragments (one-time) ----
  // B-frag layout for 16x16x32: lane holds B[k = quad*8 + j][n = l16].
  bf16x8 bfrag[4][5];
  float4_t bias4[4];
#pragma unroll
  for (int g = 0; g < 4; ++g) {
    const float scale = (g == 2) ? (-2.0f*LOG2E) : (-LOG2E);
    const int col = g*NH + w*16 + l16;
#pragma unroll
    for (int kc = 0; kc < 5; ++kc) {
      const float* src = (kc == 0) ? (Wih + ((size_t)net*FH + col)*NP + quad*8)
                                   : (Whh + ((size_t)net*FH + col)*NH + (kc-1)*32 + quad*8);
      bf16x8 bf;
#pragma unroll
      for (int j = 0; j < 8; ++j) bf[j] = (__bf16)(src[j] * scale);
      bfrag[g][kc] = bf;
    }
    const float b = (bih[net*FH + col] + bhh[net*FH + col]) * scale;
    bias4[g] = (float4_t){b, b, b, b};
  }

  // head B-frags: B[k][n] = wout[k] broadcast over all 16 cols n.
  bf16x8 wof[4];
#pragma unroll
  for (int kc = 0; kc < 4; ++kc) {
    const float* wp = Wout + net*NH + kc*32 + quad*8;
#pragma unroll
    for (int j = 0; j < 8; ++j) wof[kc][j] = (__bf16)wp[j];
  }
  const float bo = bout[net];

  // c state, PRE-SCALED by -2log2e (saves a mul on the h critical chain)
  float cs = 0.f;
  const float S2 = -2.0f*LOG2E;

  // x A-frag source: row l16 -> batch bq*2 + (l16&1) (8x dup)
  const float* xrow = X + (size_t)(bq*2 + (l16 & 1))*(NT*NP) + quad*8;

  // h write coords for unit u = w*16 + l16; row = quad&1 (lane's batch)
  const int kcp = w >> 1, q2 = ((w & 1) << 1) | (l16 >> 3), jj = l16 & 7;
  const int mrow = quad & 1;

  // head store base: out[(bq*2 + r)*NT*NP + t*NP + net], stored by
  // wave 0, lane 0 (C regs 0,1 = batches 0,1).
  float* outp = out + ((size_t)bq*2)*(NT*NP) + net;

  // preload + convert x for t=0; xp then walks t=1..NT-1
  bf16x8 ax;
  {
    float xv0[8];
    *(float4_t*)&xv0[0] = *(const float4_t*)xrow;
    *(float4_t*)&xv0[4] = *(const float4_t*)(xrow + 4);
#pragma unroll
    for (int j = 0; j < 8; ++j) ax[j] = (__bf16)xv0[j];
  }
  const float* xp = xrow + NP;
  float xv[8] = {0.f,0.f,0.f,0.f,0.f,0.f,0.f,0.f};

  for (int t = 0; t < NT; ++t) {
    const int rd = t & 1, wr = rd ^ 1;

    // ---- 1. h A-frags (row = l16&1; 8-lane same-address broadcast) ----
    bf16x8 ah[4];
#pragma unroll
    for (int kc = 0; kc < 4; ++kc)
      ah[kc] = *(const bf16x8*)&hfrag[rd][kc][quad][l16 & 1][0];

    // ---- 2. x-MFMAs first: no LDS dependence, fills ds_read latency ----
    float4_t accx[4];
#pragma unroll
    for (int g = 0; g < 4; ++g)
      accx[g] = mfma_bf16(ax, bfrag[g][0], bias4[g]);

    // ---- 3. x prefetch for t+1 (scalar-guarded, pointer-incremented) ----
    if (t + 1 < NT) {
      *(float4_t*)&xv[0] = *(const float4_t*)xp;
      *(float4_t*)&xv[4] = *(const float4_t*)(xp + 4);
    }

    // ---- 4. h-MFMAs: 4 gates, two parallel chains each (depth 2) ----
    float4_t acc[4];
#pragma unroll
    for (int g = 0; g < 4; ++g) {
      float4_t a0 = mfma_bf16(ah[0], bfrag[g][1], accx[g]);
      float4_t a1 = mfma_bf16(ah[2], bfrag[g][3], (float4_t){0.f,0.f,0.f,0.f});
      a0 = mfma_bf16(ah[1], bfrag[g][2], a0);
      a1 = mfma_bf16(ah[3], bfrag[g][4], a1);
      acc[g] = a0 + a1;
    }

    // ---- 5. select this lane's batch (= quad&1): ONE cndmask per gate ----
    float gv[4];
#pragma unroll
    for (int g = 0; g < 4; ++g)
      gv[g] = (quad & 1) ? acc[g][1] : acc[g][0];

    // ---- 6. activation + state update: ONE (batch,unit) pair per lane ----
    // (quads 2,3 duplicate quads 0,1 — harmless, keeps all lanes uniform)
    float h;
    {
      float ei = __builtin_amdgcn_exp2f(gv[0]);
      float ig = __builtin_amdgcn_rcpf(1.0f + ei);            // sigmoid(i)
      float ef = __builtin_amdgcn_exp2f(gv[1]);
      float fg = __builtin_amdgcn_rcpf(1.0f + ef);            // sigmoid(f)
      float eg = __builtin_amdgcn_exp2f(fminf(gv[2], 126.0f));
      float rg = __builtin_amdgcn_rcpf(1.0f + eg);
      float t0 = S2 * rg;
      float gg2 = t0 - t0 * eg;                               // tanh(g)*S2
      float eo = __builtin_amdgcn_exp2f(gv[3]);
      float og = __builtin_amdgcn_rcpf(1.0f + eo);            // sigmoid(o)
      cs = fg * cs + ig * gg2;                                // c * S2
      float ec = __builtin_amdgcn_exp2f(fminf(cs, 126.0f));
      float rc = __builtin_amdgcn_rcpf(1.0f + ec);
      float th = rc - ec * rc;                                // tanh(c)
      h = og * th;
    }

    // ---- 7. write h' (bf16): 1 ds_write_b16, rows 0,1 only (quads 0,1) --
    if (quad < 2)
      hfrag[wr][kcp][q2][mrow][jj] = (__bf16)h;

    // ---- 8. fused head (wave 0; ah = h_{t-1} -> out[t-1]) ----
    if (w == 0 && t > 0) {
      float4_t p0 = {bo, bo, bo, bo};
      float4_t p1 = {0.f, 0.f, 0.f, 0.f};
      p0 = mfma_bf16(ah[0], wof[0], p0);
      p1 = mfma_bf16(ah[2], wof[2], p1);
      p0 = mfma_bf16(ah[1], wof[1], p0);
      p1 = mfma_bf16(ah[3], wof[3], p1);
      float4_t po = p0 + p1;
      if (lane == 0) {   // C regs 0,1 = batches 0,1
#pragma unroll
        for (int r = 0; r < 2; ++r)
          outp[(size_t)r*(NT*NP) + (t - 1)*NP] = po[r];
      }
    }

    // ---- 9. convert next x; advance pointer ----
#pragma unroll
    for (int j = 0; j < 8; ++j) ax[j] = (__bf16)xv[j];
    xp += NP;

    BAR();  // lgkmcnt-only barrier
  }

  // ---- epilogue: head for t = NT-1 (h_{NT-1} is in hfrag[NT&1]) ----
  if (w == 0) {
    bf16x8 ahf[4];
#pragma unroll
    for (int kc = 0; kc < 4; ++kc)
      ahf[kc] = *(const bf16x8*)&hfrag[NT & 1][kc][quad][l16 & 1][0];
    float4_t p0 = {bo, bo, bo, bo};
    float4_t p1 = {0.f, 0.f, 0.f, 0.f};
    p0 = mfma_bf16(ahf[0], wof[0], p0);
    p1 = mfma_bf16(ahf[2], wof[2], p1);
    p0 = mfma_bf16(ahf[1], wof[1], p0);
    p1 = mfma_bf16(ahf[3], wof[3], p1);
    float4_t po = p0 + p1;
    if (lane == 0) {
#pragma unroll
      for (int r = 0; r < 2; ++r)
        outp[(size_t)r*(NT*NP) + (NT - 1)*NP] = po[r];
    }
  }
}

extern "C" void kernel_launch(void* const* d_in, const int* in_sizes, int n_in,
                              void* d_out, int out_size, void* d_ws, size_t ws_size,
                              hipStream_t stream) {
  const float* X    = (const float*)d_in[0];
  const float* Wih  = (const float*)d_in[1];
  const float* Whh  = (const float*)d_in[2];
  const float* bih  = (const float*)d_in[3];
  const float* bhh  = (const float*)d_in[4];
  const float* Wout = (const float*)d_in[5];
  const float* bout = (const float*)d_in[6];
  float* out = (float*)d_out;
  (void)in_sizes; (void)n_in; (void)out_size; (void)d_ws; (void)ws_size;

  // 512 blocks = 32 nets x 16 batch-groups (M=2); 2 blocks co-resident/CU
  // (108 VGPR x 4 waves = 432 <= 512, HW-scheduled, no compiler hint).
  clstm_fused<<<512, 512, 0, stream>>>(X, Wih, Whh, bih, bhh, Wout, bout, out);
}